// Round 5
// baseline (110.129 us; speedup 1.0000x reference)
//
#include <hip/hip_runtime.h>
#include <hip/hip_bf16.h>

#define D_DIM 256
#define K_CODES 1024
#define N_ROWS (32 * 1024)
#define BLOCK_ROWS 32                 // rows per block (2 MFMA row-sets / wave)
#define NBLK (N_ROWS / BLOCK_ROWS)    // 1024 main blocks

typedef __attribute__((ext_vector_type(8))) short bf16x8;
typedef __attribute__((ext_vector_type(4))) float f32x4;

static __device__ __forceinline__ short f2bf(float f) {
    __hip_bfloat16 h = __float2bfloat16(f);   // RNE
    return *reinterpret_cast<short*>(&h);
}

static __device__ __forceinline__ bf16x8 pack8(float4 a, float4 b) {
    bf16x8 r;
    r[0] = f2bf(a.x); r[1] = f2bf(a.y); r[2] = f2bf(a.z); r[3] = f2bf(a.w);
    r[4] = f2bf(b.x); r[5] = f2bf(b.y); r[6] = f2bf(b.z); r[7] = f2bf(b.w);
    return r;
}

// ---------------------------------------------------------------- prep
// Fused: (a) enorm[k] = ||E[k]||^2  (one wave per code row)
//        (b) Eb = bf16(-2*E) in MFMA B-fragment order (blocks 0..127)
// frag g = t*512 + kk*64 + l holds E[code = t*16 + (l&15)][d = kk*32 + (l>>4)*8 ..+8]
__global__ __launch_bounds__(256) void vq_prep(const float* __restrict__ E,
                                               float* __restrict__ enorm,
                                               short* __restrict__ Eb) {
    int wave = threadIdx.x >> 6;
    int lane = threadIdx.x & 63;
    int k = blockIdx.x * 4 + wave;               // [0,1024)
    const float4 v = *reinterpret_cast<const float4*>(E + k * D_DIM + lane * 4);
    float s = v.x * v.x + v.y * v.y + v.z * v.z + v.w * v.w;
    #pragma unroll
    for (int off = 32; off; off >>= 1) s += __shfl_xor(s, off, 64);
    if (lane == 0) enorm[k] = s;

    if (blockIdx.x < 128) {
        int g = blockIdx.x * 256 + threadIdx.x;  // [0, 32768)
        int t = g >> 9;
        int kk = (g >> 6) & 7;
        int l = g & 63;
        int code = t * 16 + (l & 15);
        int d = kk * 32 + ((l >> 4) << 3);
        const float* src = E + (size_t)code * D_DIM + d;
        float4 v0 = *reinterpret_cast<const float4*>(src);
        float4 v1 = *reinterpret_cast<const float4*>(src + 4);
        v0.x *= -2.f; v0.y *= -2.f; v0.z *= -2.f; v0.w *= -2.f;
        v1.x *= -2.f; v1.y *= -2.f; v1.z *= -2.f; v1.w *= -2.f;
        *reinterpret_cast<bf16x8*>(Eb + (size_t)g * 8) = pack8(v0, v1);
    }
}

// ---------------------------------------------------------------- main
// Block = 32 rows; 4 waves K-split (wave w -> codes [w*256, w*256+256)).
// X rows in registers (2 bf16 A-frag sets); B fragments in a 3-deep ring
// (fully unrolled => static indices); split-K accumulators (4 indep chains);
// enorm preloaded to registers; nontemporal output stores.
__global__ __launch_bounds__(256, 2) void vq_main(const float* __restrict__ X,
                                                  const float* __restrict__ E,
                                                  const float* __restrict__ enorm,
                                                  const short* __restrict__ Eb,
                                                  float* __restrict__ outq,
                                                  float* __restrict__ loss_partial) {
    __shared__ float mv[4][BLOCK_ROWS];
    __shared__ int   mi[4][BLOCK_ROWS];
    __shared__ int   fidx[BLOCK_ROWS];
    __shared__ float wsum[4];

    const int tid  = threadIdx.x;
    const int wave = tid >> 6;
    const int l    = tid & 63;
    const int lr   = l & 15;      // row-in-16 (A) / code col (B,C)
    const int lk   = l >> 4;      // k-group
    const int brow0 = blockIdx.x * BLOCK_ROWS;
    const int wbase = wave * 16;  // this wave's first 16-code tile index

    const bf16x8* Ebf = (const bf16x8*)Eb;
    bf16x8 b[3][8];

#define LOADB(SLOT, T)                                                        \
    do {                                                                      \
        _Pragma("unroll")                                                     \
        for (int kk = 0; kk < 8; ++kk)                                        \
            b[SLOT][kk] = Ebf[(size_t)(wbase + (T)) * 512 + kk * 64 + l];     \
    } while (0)

    // issue first two B tiles before the (long) X prologue
    LOADB(0, 0);
    LOADB(1, 1);

    // enorm for this wave's 256 codes, one value per tile per lane
    float en_r[16];
    #pragma unroll
    for (int t = 0; t < 16; ++t)
        en_r[t] = enorm[(wbase + t) * 16 + lr];

    // 32 rows of X -> bf16 A-fragments (same for all waves)
    bf16x8 a[2][8];
    #pragma unroll
    for (int s = 0; s < 2; ++s) {
        const float* xp = X + (size_t)(brow0 + s * 16 + lr) * D_DIM + lk * 8;
        #pragma unroll
        for (int kk = 0; kk < 8; ++kk) {
            float4 p = *reinterpret_cast<const float4*>(xp + kk * 32);
            float4 q = *reinterpret_cast<const float4*>(xp + kk * 32 + 4);
            a[s][kk] = pack8(p, q);
        }
    }

    float minv[2][4];
    int   mini[2][4];
    #pragma unroll
    for (int s = 0; s < 2; ++s)
        #pragma unroll
        for (int i = 0; i < 4; ++i) { minv[s][i] = INFINITY; mini[s][i] = 0; }

#define COMPUTE(SLOT, TT)                                                     \
    do {                                                                      \
        f32x4 accA0 = {0, 0, 0, 0}, accA1 = {0, 0, 0, 0};                     \
        f32x4 accB0 = {0, 0, 0, 0}, accB1 = {0, 0, 0, 0};                     \
        _Pragma("unroll")                                                     \
        for (int j = 0; j < 4; ++j) {                                         \
            accA0 = __builtin_amdgcn_mfma_f32_16x16x32_bf16(                  \
                a[0][j], b[SLOT][j], accA0, 0, 0, 0);                         \
            accA1 = __builtin_amdgcn_mfma_f32_16x16x32_bf16(                  \
                a[1][j], b[SLOT][j], accA1, 0, 0, 0);                         \
            accB0 = __builtin_amdgcn_mfma_f32_16x16x32_bf16(                  \
                a[0][j + 4], b[SLOT][j + 4], accB0, 0, 0, 0);                 \
            accB1 = __builtin_amdgcn_mfma_f32_16x16x32_bf16(                  \
                a[1][j + 4], b[SLOT][j + 4], accB1, 0, 0, 0);                 \
        }                                                                     \
        const int idx_ = (wbase + (TT)) * 16 + lr;                            \
        const float en_ = en_r[TT];                                           \
        _Pragma("unroll")                                                     \
        for (int i = 0; i < 4; ++i) {                                         \
            float s0 = accA0[i] + accB0[i] + en_;                             \
            float s1 = accA1[i] + accB1[i] + en_;                             \
            if (s0 < minv[0][i]) { minv[0][i] = s0; mini[0][i] = idx_; }      \
            if (s1 < minv[1][i]) { minv[1][i] = s1; mini[1][i] = idx_; }      \
        }                                                                     \
    } while (0)

    // 16 tiles, 3-deep ring, fully unrolled (static ring indices)
    #pragma unroll
    for (int tt = 0; tt < 16; ++tt) {
        if (tt < 14) LOADB((tt + 2) % 3, tt + 2);
        COMPUTE(tt % 3, tt);
    }
#undef COMPUTE
#undef LOADB

    // ---- reduce over the 16 code-lanes (first-min tie-break)
    #pragma unroll
    for (int off = 8; off >= 1; off >>= 1) {
        #pragma unroll
        for (int s = 0; s < 2; ++s)
            #pragma unroll
            for (int i = 0; i < 4; ++i) {
                float ov = __shfl_xor(minv[s][i], off, 64);
                int   oi = __shfl_xor(mini[s][i], off, 64);
                if (ov < minv[s][i] || (ov == minv[s][i] && oi < mini[s][i])) {
                    minv[s][i] = ov; mini[s][i] = oi;
                }
            }
    }

    // ---- publish per-wave results, merge the 4 K-split waves
    if (lr == 0) {
        #pragma unroll
        for (int s = 0; s < 2; ++s)
            #pragma unroll
            for (int i = 0; i < 4; ++i) {
                mv[wave][s * 16 + lk * 4 + i] = minv[s][i];
                mi[wave][s * 16 + lk * 4 + i] = mini[s][i];
            }
    }
    __syncthreads();
    if (tid < BLOCK_ROWS) {
        float bv = mv[0][tid]; int bi = mi[0][tid];
        #pragma unroll
        for (int w = 1; w < 4; ++w) {
            float v = mv[w][tid]; int ii = mi[w][tid];
            if (v < bv || (v == bv && ii < bi)) { bv = v; bi = ii; }
        }
        fidx[tid] = bi;
    }
    __syncthreads();

    // ---- fused gather-writeback + loss (8 threads per row)
    float lsum = 0.0f;
    {
        const int r   = tid >> 3;       // 0..31
        const int c8  = tid & 7;
        const int row = brow0 + r;
        const int idx = fidx[r];
        const float* eq  = E + (size_t)idx * D_DIM;
        const float* xr  = X + (size_t)row * D_DIM;
        float*       orw = outq + (size_t)row * D_DIM;
        #pragma unroll
        for (int j = 0; j < 8; ++j) {
            int d = c8 * 4 + j * 32;
            float4 q = *reinterpret_cast<const float4*>(eq + d);
            float4 x = *reinterpret_cast<const float4*>(xr + d);
            f32x4 qv = {q.x, q.y, q.z, q.w};
            __builtin_nontemporal_store(qv, reinterpret_cast<f32x4*>(orw + d));
            float dx = q.x - x.x, dy = q.y - x.y, dz = q.z - x.z, dw = q.w - x.w;
            lsum += dx * dx + dy * dy + dz * dz + dw * dw;
        }
    }
    #pragma unroll
    for (int off = 32; off; off >>= 1) lsum += __shfl_xor(lsum, off, 64);
    if (l == 0) wsum[wave] = lsum;
    __syncthreads();
    if (tid == 0)
        loss_partial[blockIdx.x] = wsum[0] + wsum[1] + wsum[2] + wsum[3];
}

// ---------------------------------------------------------------- finalize
// deterministic fold of 1024 block partials -> vq_loss scalar
__global__ __launch_bounds__(256) void vq_finalize(const float* __restrict__ partials,
                                                   float* __restrict__ out_loss) {
    __shared__ float s[256];
    int t = threadIdx.x;
    s[t] = partials[t] + partials[t + 256] + partials[t + 512] + partials[t + 768];
    __syncthreads();
    #pragma unroll
    for (int off = 128; off; off >>= 1) {
        if (t < off) s[t] += s[t + off];
        __syncthreads();
    }
    if (t == 0)
        out_loss[0] = s[0] * (1.25f / (float)((size_t)N_ROWS * D_DIM));
}

// ---------------------------------------------------------------- launch
extern "C" void kernel_launch(void* const* d_in, const int* in_sizes, int n_in,
                              void* d_out, int out_size, void* d_ws, size_t ws_size,
                              hipStream_t stream) {
    const float* X = (const float*)d_in[0];   // latents  [32768, 256] f32
    const float* E = (const float*)d_in[1];   // codebook [1024, 256]  f32
    float* out = (float*)d_out;               // 8388608 quantized + 1 loss

    float* enorm    = (float*)d_ws;                       // 1024 f32
    float* partials = enorm + K_CODES;                    // 1024 f32
    short* Eb       = (short*)(partials + NBLK);          // 512 KB bf16, 16B-aligned

    vq_prep    <<<256,  256, 0, stream>>>(E, enorm, Eb);
    vq_main    <<<NBLK, 256, 0, stream>>>(X, E, enorm, Eb, out, partials);
    vq_finalize<<<1,    256, 0, stream>>>(partials, out + (size_t)N_ROWS * D_DIM);
}

// Round 6
// 56.054 us; speedup vs baseline: 1.9647x; 1.9647x over previous
//
#include <hip/hip_runtime.h>
#include <hip/hip_bf16.h>

#define D_DIM 256
#define K_CODES 1024
#define N_ROWS (32 * 1024)
#define BLOCK_ROWS 64                 // rows per block (2 row-groups x 32)
#define NBLK (N_ROWS / BLOCK_ROWS)    // 512 main blocks
#define STEPS 32                      // 16-code tiles per K-group (512 codes)

typedef __attribute__((ext_vector_type(8))) short bf16x8;
typedef __attribute__((ext_vector_type(4))) float f32x4;

static __device__ __forceinline__ short f2bf(float f) {
    __hip_bfloat16 h = __float2bfloat16(f);   // RNE
    return *reinterpret_cast<short*>(&h);
}

static __device__ __forceinline__ bf16x8 pack8(float4 a, float4 b) {
    bf16x8 r;
    r[0] = f2bf(a.x); r[1] = f2bf(a.y); r[2] = f2bf(a.z); r[3] = f2bf(a.w);
    r[4] = f2bf(b.x); r[5] = f2bf(b.y); r[6] = f2bf(b.z); r[7] = f2bf(b.w);
    return r;
}

static __device__ __forceinline__ void gload_lds16(const void* g, void* s) {
    __builtin_amdgcn_global_load_lds(
        (const __attribute__((address_space(1))) void*)g,
        (__attribute__((address_space(3))) void*)s, 16, 0, 0);
}

// ---------------------------------------------------------------- prep
// Fused: (a) enorm[k] = ||E[k]||^2  (one wave per code row)
//        (b) Eb = bf16(-2*E) in MFMA B-fragment order (blocks 0..127)
// frag g = t*512 + kk*64 + l holds E[code = t*16 + (l&15)][d = kk*32 + (l>>4)*8 ..+8]
__global__ __launch_bounds__(256) void vq_prep(const float* __restrict__ E,
                                               float* __restrict__ enorm,
                                               short* __restrict__ Eb) {
    int wave = threadIdx.x >> 6;
    int lane = threadIdx.x & 63;
    int k = blockIdx.x * 4 + wave;               // [0,1024)
    const float4 v = *reinterpret_cast<const float4*>(E + k * D_DIM + lane * 4);
    float s = v.x * v.x + v.y * v.y + v.z * v.z + v.w * v.w;
    #pragma unroll
    for (int off = 32; off; off >>= 1) s += __shfl_xor(s, off, 64);
    if (lane == 0) enorm[k] = s;

    if (blockIdx.x < 128) {
        int g = blockIdx.x * 256 + threadIdx.x;  // [0, 32768)
        int t = g >> 9;
        int kk = (g >> 6) & 7;
        int l = g & 63;
        int code = t * 16 + (l & 15);
        int d = kk * 32 + ((l >> 4) << 3);
        const float* src = E + (size_t)code * D_DIM + d;
        float4 v0 = *reinterpret_cast<const float4*>(src);
        float4 v1 = *reinterpret_cast<const float4*>(src + 4);
        v0.x *= -2.f; v0.y *= -2.f; v0.z *= -2.f; v0.w *= -2.f;
        v1.x *= -2.f; v1.y *= -2.f; v1.z *= -2.f; v1.w *= -2.f;
        *reinterpret_cast<bf16x8*>(Eb + (size_t)g * 8) = pack8(v0, v1);
    }
}

// ---------------------------------------------------------------- main
// Block = 64 rows, 4 waves = (kg in {0,1}) x (rg in {0,1}).
// Wave (kg,rg): rows [rg*32, rg*32+32), codes [kg*512, kg*512+512).
// B tiles (16 codes = 8KB, fragment order) double-buffered in LDS via
// global_load_lds; both rg-waves of a kg read the same staged tile.
// A (X rows) in registers as bf16 frags. One __syncthreads per step.
__global__ __launch_bounds__(256, 2) void vq_main(const float* __restrict__ X,
                                                  const float* __restrict__ E,
                                                  const float* __restrict__ enorm,
                                                  const short* __restrict__ Eb,
                                                  float* __restrict__ outq,
                                                  float* __restrict__ loss_partial) {
    __shared__ short lds[2][2][4096];   // [kg][buf][8KB tile] = 32 KB
    __shared__ float mv[2][BLOCK_ROWS];
    __shared__ int   mi[2][BLOCK_ROWS];
    __shared__ int   fidx[BLOCK_ROWS];
    __shared__ float wsum[4];

    const int tid  = threadIdx.x;
    const int wave = tid >> 6;
    const int kg   = wave >> 1;   // K-group: codes [kg*512, kg*512+512)
    const int rg   = wave & 1;    // row-group: rows [rg*32, rg*32+32)
    const int l    = tid & 63;
    const int lr   = l & 15;      // row-in-16 (A) / code col (B,C)
    const int lk   = l >> 4;      // k-group-of-8
    const int brow0 = blockIdx.x * BLOCK_ROWS;
    const int row0  = brow0 + rg * 32;

    // stage: this wave stages 4 of the 8 kk-chunks of its kg's next tile
#define STAGE(TT, BUF)                                                        \
    do {                                                                      \
        if ((TT) < STEPS) {                                                   \
            const int tg_ = kg * STEPS + (TT);                                \
            _Pragma("unroll")                                                 \
            for (int kv = 0; kv < 4; ++kv) {                                  \
                const int kk_ = rg * 4 + kv;                                  \
                gload_lds16(Eb + ((size_t)tg_ * 512 + kk_ * 64 + l) * 8,      \
                            &lds[kg][BUF][kk_ * 512]);                        \
            }                                                                 \
        }                                                                     \
    } while (0)

    STAGE(0, 0);   // issue tile-0 staging before the long X prologue

    // ---- prologue: this wave's 32 rows of X -> bf16 A-fragments
    bf16x8 a[2][8];
    #pragma unroll
    for (int s = 0; s < 2; ++s) {
        const float* xp = X + (size_t)(row0 + s * 16 + lr) * D_DIM + lk * 8;
        #pragma unroll
        for (int kk = 0; kk < 8; ++kk) {
            float4 p = *reinterpret_cast<const float4*>(xp + kk * 32);
            float4 q = *reinterpret_cast<const float4*>(xp + kk * 32 + 4);
            a[s][kk] = pack8(p, q);
        }
    }

    float minv[2][4];
    int   mini[2][4];
    #pragma unroll
    for (int s = 0; s < 2; ++s)
        #pragma unroll
        for (int i = 0; i < 4; ++i) { minv[s][i] = INFINITY; mini[s][i] = 0; }

    __syncthreads();   // tile 0 staged (syncthreads drains vmcnt)

    for (int tt = 0; tt < STEPS; ++tt) {
        const int buf = tt & 1;
        STAGE(tt + 1, buf ^ 1);

        const int tg = kg * STEPS + tt;
        const float en = enorm[tg * 16 + lr];   // issued early, used late

        bf16x8 b[8];
        #pragma unroll
        for (int kk = 0; kk < 8; ++kk)
            b[kk] = *reinterpret_cast<const bf16x8*>(&lds[kg][buf][kk * 512 + l * 8]);

        f32x4 acc0 = {0, 0, 0, 0}, acc1 = {0, 0, 0, 0};
        #pragma unroll
        for (int kk = 0; kk < 8; ++kk) {
            acc0 = __builtin_amdgcn_mfma_f32_16x16x32_bf16(a[0][kk], b[kk], acc0, 0, 0, 0);
            acc1 = __builtin_amdgcn_mfma_f32_16x16x32_bf16(a[1][kk], b[kk], acc1, 0, 0, 0);
        }

        const int idx = tg * 16 + lr;
        #pragma unroll
        for (int i = 0; i < 4; ++i) {
            float s0 = acc0[i] + en;
            float s1 = acc1[i] + en;
            if (s0 < minv[0][i]) { minv[0][i] = s0; mini[0][i] = idx; }
            if (s1 < minv[1][i]) { minv[1][i] = s1; mini[1][i] = idx; }
        }

        __syncthreads();   // tile tt+1 staged; all reads of buf done
    }
#undef STAGE

    // ---- reduce over the 16 code-lanes (first-min tie-break)
    #pragma unroll
    for (int off = 8; off >= 1; off >>= 1) {
        #pragma unroll
        for (int s = 0; s < 2; ++s)
            #pragma unroll
            for (int i = 0; i < 4; ++i) {
                float ov = __shfl_xor(minv[s][i], off, 64);
                int   oi = __shfl_xor(mini[s][i], off, 64);
                if (ov < minv[s][i] || (ov == minv[s][i] && oi < mini[s][i])) {
                    minv[s][i] = ov; mini[s][i] = oi;
                }
            }
    }

    // ---- publish per-wave results, merge the 2 K-groups
    if (lr == 0) {
        #pragma unroll
        for (int s = 0; s < 2; ++s)
            #pragma unroll
            for (int i = 0; i < 4; ++i) {
                mv[kg][rg * 32 + s * 16 + lk * 4 + i] = minv[s][i];
                mi[kg][rg * 32 + s * 16 + lk * 4 + i] = mini[s][i];
            }
    }
    __syncthreads();
    if (tid < BLOCK_ROWS) {
        float bv = mv[0][tid]; int bi = mi[0][tid];
        float v  = mv[1][tid]; int ii = mi[1][tid];
        if (v < bv || (v == bv && ii < bi)) { bv = v; bi = ii; }
        fidx[tid] = bi;
    }
    __syncthreads();

    // ---- fused gather-writeback + loss (8 threads per row, 2 halves)
    float lsum = 0.0f;
    #pragma unroll
    for (int h = 0; h < 2; ++h) {
        const int r   = (tid >> 3) + h * 32;
        const int c8  = tid & 7;
        const int row = brow0 + r;
        const int idx = fidx[r];
        const float* eq  = E + (size_t)idx * D_DIM;
        const float* xr  = X + (size_t)row * D_DIM;
        float*       orw = outq + (size_t)row * D_DIM;
        #pragma unroll
        for (int j = 0; j < 8; ++j) {
            int d = c8 * 4 + j * 32;
            float4 q = *reinterpret_cast<const float4*>(eq + d);
            float4 x = *reinterpret_cast<const float4*>(xr + d);
            f32x4 qv = {q.x, q.y, q.z, q.w};
            __builtin_nontemporal_store(qv, reinterpret_cast<f32x4*>(orw + d));
            float dx = q.x - x.x, dy = q.y - x.y, dz = q.z - x.z, dw = q.w - x.w;
            lsum += dx * dx + dy * dy + dz * dz + dw * dw;
        }
    }
    #pragma unroll
    for (int off = 32; off; off >>= 1) lsum += __shfl_xor(lsum, off, 64);
    if (l == 0) wsum[wave] = lsum;
    __syncthreads();
    if (tid == 0)
        loss_partial[blockIdx.x] = wsum[0] + wsum[1] + wsum[2] + wsum[3];
}

// ---------------------------------------------------------------- finalize
// deterministic fold of 512 block partials -> vq_loss scalar
__global__ __launch_bounds__(256) void vq_finalize(const float* __restrict__ partials,
                                                   float* __restrict__ out_loss) {
    __shared__ float s[256];
    int t = threadIdx.x;
    s[t] = partials[t] + partials[t + 256];
    __syncthreads();
    #pragma unroll
    for (int off = 128; off; off >>= 1) {
        if (t < off) s[t] += s[t + off];
        __syncthreads();
    }
    if (t == 0)
        out_loss[0] = s[0] * (1.25f / (float)((size_t)N_ROWS * D_DIM));
}

// ---------------------------------------------------------------- launch
extern "C" void kernel_launch(void* const* d_in, const int* in_sizes, int n_in,
                              void* d_out, int out_size, void* d_ws, size_t ws_size,
                              hipStream_t stream) {
    const float* X = (const float*)d_in[0];   // latents  [32768, 256] f32
    const float* E = (const float*)d_in[1];   // codebook [1024, 256]  f32
    float* out = (float*)d_out;               // 8388608 quantized + 1 loss

    float* enorm    = (float*)d_ws;                       // 1024 f32
    float* partials = enorm + K_CODES;                    // 512 f32 (1024 slot)
    short* Eb       = (short*)(partials + 1024);          // 512 KB bf16, 16B-aligned

    vq_prep    <<<256,  256, 0, stream>>>(E, enorm, Eb);
    vq_main    <<<NBLK, 256, 0, stream>>>(X, E, enorm, Eb, out, partials);
    vq_finalize<<<1,    256, 0, stream>>>(partials, out + (size_t)N_ROWS * D_DIM);
}

// Round 7
// 47.124 us; speedup vs baseline: 2.3370x; 1.1895x over previous
//
#include <hip/hip_runtime.h>
#include <hip/hip_bf16.h>

#define D_DIM 256
#define K_CODES 1024
#define N_ROWS (32 * 1024)
#define BLOCK_ROWS 64                 // rows per block (2 row-groups x 32)
#define NBLK (N_ROWS / BLOCK_ROWS)    // 512 main blocks
#define STEPS 32                      // 16-code tiles per K-group (512 codes)
#define TILE_SH 4128                  // shorts per LDS tile: 8KB frags + 64B enorm

typedef __attribute__((ext_vector_type(8))) short bf16x8;
typedef __attribute__((ext_vector_type(4))) float f32x4;

#define MFMA16 __builtin_amdgcn_mfma_f32_16x16x32_bf16

static __device__ __forceinline__ short f2bf(float f) {
    __hip_bfloat16 h = __float2bfloat16(f);   // RNE
    return *reinterpret_cast<short*>(&h);
}

static __device__ __forceinline__ bf16x8 pack8(float4 a, float4 b) {
    bf16x8 r;
    r[0] = f2bf(a.x); r[1] = f2bf(a.y); r[2] = f2bf(a.z); r[3] = f2bf(a.w);
    r[4] = f2bf(b.x); r[5] = f2bf(b.y); r[6] = f2bf(b.z); r[7] = f2bf(b.w);
    return r;
}

static __device__ __forceinline__ void gload_lds16(const void* g, void* s) {
    __builtin_amdgcn_global_load_lds(
        (const __attribute__((address_space(1))) void*)g,
        (__attribute__((address_space(3))) void*)s, 16, 0, 0);
}
static __device__ __forceinline__ void gload_lds4(const void* g, void* s) {
    __builtin_amdgcn_global_load_lds(
        (const __attribute__((address_space(1))) void*)g,
        (__attribute__((address_space(3))) void*)s, 4, 0, 0);
}

// ---------------------------------------------------------------- prep
// Fused: (a) enorm[k] = ||E[k]||^2  (one wave per code row)
//        (b) Eb = bf16(-2*E) in MFMA B-fragment order (blocks 0..127)
// frag g = t*512 + kk*64 + l holds E[code = t*16 + (l&15)][d = kk*32 + (l>>4)*8 ..+8]
__global__ __launch_bounds__(256) void vq_prep(const float* __restrict__ E,
                                               float* __restrict__ enorm,
                                               short* __restrict__ Eb) {
    int wave = threadIdx.x >> 6;
    int lane = threadIdx.x & 63;
    int k = blockIdx.x * 4 + wave;               // [0,1024)
    const float4 v = *reinterpret_cast<const float4*>(E + k * D_DIM + lane * 4);
    float s = v.x * v.x + v.y * v.y + v.z * v.z + v.w * v.w;
    #pragma unroll
    for (int off = 32; off; off >>= 1) s += __shfl_xor(s, off, 64);
    if (lane == 0) enorm[k] = s;

    if (blockIdx.x < 128) {
        int g = blockIdx.x * 256 + threadIdx.x;  // [0, 32768)
        int t = g >> 9;
        int kk = (g >> 6) & 7;
        int l = g & 63;
        int code = t * 16 + (l & 15);
        int d = kk * 32 + ((l >> 4) << 3);
        const float* src = E + (size_t)code * D_DIM + d;
        float4 v0 = *reinterpret_cast<const float4*>(src);
        float4 v1 = *reinterpret_cast<const float4*>(src + 4);
        v0.x *= -2.f; v0.y *= -2.f; v0.z *= -2.f; v0.w *= -2.f;
        v1.x *= -2.f; v1.y *= -2.f; v1.z *= -2.f; v1.w *= -2.f;
        *reinterpret_cast<bf16x8*>(Eb + (size_t)g * 8) = pack8(v0, v1);
    }
}

// ---------------------------------------------------------------- main
// Block = 64 rows, 4 waves = (kg in {0,1}) x (rg in {0,1}).
// Triple-buffered LDS B-tiles staged 2 steps ahead via global_load_lds.
// Raw s_barrier + counted s_waitcnt vmcnt(5): staging stays in flight
// across barriers (T3/T4). enorm rides inside the staged tile (no per-step
// global scalar load to pollute the counted vmcnt).
__global__ __launch_bounds__(256, 2) void vq_main(const float* __restrict__ X,
                                                  const float* __restrict__ E,
                                                  const float* __restrict__ enorm,
                                                  const short* __restrict__ Eb,
                                                  float* __restrict__ outq,
                                                  float* __restrict__ loss_partial) {
    __shared__ short lds[2][3][TILE_SH];   // ~49.5 KB
    __shared__ float mv[2][BLOCK_ROWS];
    __shared__ int   mi[2][BLOCK_ROWS];
    __shared__ int   fidx[BLOCK_ROWS];
    __shared__ float wsum[4];

    const int tid  = threadIdx.x;
    const int wave = tid >> 6;
    const int kg   = wave >> 1;   // K-group: codes [kg*512, kg*512+512)
    const int rg   = wave & 1;    // row-group: rows [rg*32, rg*32+32)
    const int l    = tid & 63;
    const int lr   = l & 15;      // row-in-16 (A) / code col (B,C)
    const int lk   = l >> 4;
    const int brow0 = blockIdx.x * BLOCK_ROWS;
    const int row0  = brow0 + rg * 32;

    // 5 loads per wave per stage: 4 fragment chunks + enorm (both rg waves
    // stage the same enorm words -> benign duplicate, keeps vmcnt uniform).
#define STAGE(TT, BUF)                                                        \
    do {                                                                      \
        const int tg_ = kg * STEPS + (TT);                                    \
        _Pragma("unroll")                                                     \
        for (int kv = 0; kv < 4; ++kv) {                                      \
            const int kk_ = rg * 4 + kv;                                      \
            gload_lds16(Eb + ((size_t)tg_ * 512 + kk_ * 64 + l) * 8,          \
                        &lds[kg][BUF][kk_ * 512]);                            \
        }                                                                     \
        if (l < 16) gload_lds4(enorm + tg_ * 16 + l, &lds[kg][BUF][4096]);    \
    } while (0)

    STAGE(0, 0);   // 5 loads
    STAGE(1, 1);   // 5 loads

    // ---- prologue: this wave's 32 rows of X -> bf16 A-fragments
    bf16x8 a[2][8];
    #pragma unroll
    for (int s = 0; s < 2; ++s) {
        const float* xp = X + (size_t)(row0 + s * 16 + lr) * D_DIM + lk * 8;
        #pragma unroll
        for (int kk = 0; kk < 8; ++kk) {
            float4 p = *reinterpret_cast<const float4*>(xp + kk * 32);
            float4 q = *reinterpret_cast<const float4*>(xp + kk * 32 + 4);
            a[s][kk] = pack8(p, q);
        }
    }

    float minv[2][4];
    int   mini[2][4];
    #pragma unroll
    for (int s = 0; s < 2; ++s)
        #pragma unroll
        for (int i = 0; i < 4; ++i) { minv[s][i] = INFINITY; mini[s][i] = 0; }

#define STEP(TT, LAST)                                                        \
    do {                                                                      \
        const int buf_ = (TT) % 3;                                            \
        if (LAST) { asm volatile("s_waitcnt vmcnt(0)" ::: "memory"); }        \
        else      { asm volatile("s_waitcnt vmcnt(5)" ::: "memory"); }        \
        __builtin_amdgcn_sched_barrier(0);                                    \
        __builtin_amdgcn_s_barrier();                                         \
        bf16x8 b[8];                                                          \
        _Pragma("unroll")                                                     \
        for (int kk = 0; kk < 8; ++kk)                                        \
            b[kk] = *reinterpret_cast<const bf16x8*>(                         \
                &lds[kg][buf_][kk * 512 + l * 8]);                            \
        const float en = *reinterpret_cast<const float*>(                     \
            &lds[kg][buf_][4096 + lr * 2]);                                   \
        if (!(LAST) && (TT) + 2 < STEPS) STAGE((TT) + 2, ((TT) + 2) % 3);     \
        f32x4 acc0 = {0, 0, 0, 0}, acc1 = {0, 0, 0, 0};                       \
        _Pragma("unroll")                                                     \
        for (int kk = 0; kk < 8; ++kk) {                                      \
            acc0 = MFMA16(a[0][kk], b[kk], acc0, 0, 0, 0);                    \
            acc1 = MFMA16(a[1][kk], b[kk], acc1, 0, 0, 0);                    \
        }                                                                     \
        const int idx_ = (kg * STEPS + (TT)) * 16 + lr;                       \
        _Pragma("unroll")                                                     \
        for (int i = 0; i < 4; ++i) {                                         \
            float s0 = acc0[i] + en;                                          \
            float s1 = acc1[i] + en;                                          \
            if (s0 < minv[0][i]) { minv[0][i] = s0; mini[0][i] = idx_; }      \
            if (s1 < minv[1][i]) { minv[1][i] = s1; mini[1][i] = idx_; }      \
        }                                                                     \
        __builtin_amdgcn_sched_barrier(0);                                    \
    } while (0)

    for (int tt = 0; tt < STEPS - 1; ++tt) STEP(tt, false);
    STEP(STEPS - 1, true);
#undef STEP
#undef STAGE

    // ---- reduce over the 16 code-lanes (first-min tie-break)
    #pragma unroll
    for (int off = 8; off >= 1; off >>= 1) {
        #pragma unroll
        for (int s = 0; s < 2; ++s)
            #pragma unroll
            for (int i = 0; i < 4; ++i) {
                float ov = __shfl_xor(minv[s][i], off, 64);
                int   oi = __shfl_xor(mini[s][i], off, 64);
                if (ov < minv[s][i] || (ov == minv[s][i] && oi < mini[s][i])) {
                    minv[s][i] = ov; mini[s][i] = oi;
                }
            }
    }

    // ---- publish per-wave results, merge the 2 K-groups
    if (lr == 0) {
        #pragma unroll
        for (int s = 0; s < 2; ++s)
            #pragma unroll
            for (int i = 0; i < 4; ++i) {
                mv[kg][rg * 32 + s * 16 + lk * 4 + i] = minv[s][i];
                mi[kg][rg * 32 + s * 16 + lk * 4 + i] = mini[s][i];
            }
    }
    __syncthreads();
    if (tid < BLOCK_ROWS) {
        float bv = mv[0][tid]; int bi = mi[0][tid];
        float v  = mv[1][tid]; int ii = mi[1][tid];
        if (v < bv || (v == bv && ii < bi)) { bv = v; bi = ii; }
        fidx[tid] = bi;
    }
    __syncthreads();

    // ---- fused gather-writeback + loss (8 threads per row, 2 halves)
    float lsum = 0.0f;
    #pragma unroll
    for (int h = 0; h < 2; ++h) {
        const int r   = (tid >> 3) + h * 32;
        const int c8  = tid & 7;
        const int row = brow0 + r;
        const int idx = fidx[r];
        const float* eq  = E + (size_t)idx * D_DIM;
        const float* xr  = X + (size_t)row * D_DIM;
        float*       orw = outq + (size_t)row * D_DIM;
        #pragma unroll
        for (int j = 0; j < 8; ++j) {
            int d = c8 * 4 + j * 32;
            float4 q = *reinterpret_cast<const float4*>(eq + d);
            float4 x = *reinterpret_cast<const float4*>(xr + d);
            f32x4 qv = {q.x, q.y, q.z, q.w};
            __builtin_nontemporal_store(qv, reinterpret_cast<f32x4*>(orw + d));
            float dx = q.x - x.x, dy = q.y - x.y, dz = q.z - x.z, dw = q.w - x.w;
            lsum += dx * dx + dy * dy + dz * dz + dw * dw;
        }
    }
    #pragma unroll
    for (int off = 32; off; off >>= 1) lsum += __shfl_xor(lsum, off, 64);
    if (l == 0) wsum[wave] = lsum;
    __syncthreads();
    if (tid == 0)
        loss_partial[blockIdx.x] = wsum[0] + wsum[1] + wsum[2] + wsum[3];
}

// ---------------------------------------------------------------- finalize
// deterministic fold of 512 block partials -> vq_loss scalar
__global__ __launch_bounds__(256) void vq_finalize(const float* __restrict__ partials,
                                                   float* __restrict__ out_loss) {
    __shared__ float s[256];
    int t = threadIdx.x;
    s[t] = partials[t] + partials[t + 256];
    __syncthreads();
    #pragma unroll
    for (int off = 128; off; off >>= 1) {
        if (t < off) s[t] += s[t + off];
        __syncthreads();
    }
    if (t == 0)
        out_loss[0] = s[0] * (1.25f / (float)((size_t)N_ROWS * D_DIM));
}

// ---------------------------------------------------------------- launch
extern "C" void kernel_launch(void* const* d_in, const int* in_sizes, int n_in,
                              void* d_out, int out_size, void* d_ws, size_t ws_size,
                              hipStream_t stream) {
    const float* X = (const float*)d_in[0];   // latents  [32768, 256] f32
    const float* E = (const float*)d_in[1];   // codebook [1024, 256]  f32
    float* out = (float*)d_out;               // 8388608 quantized + 1 loss

    float* enorm    = (float*)d_ws;                       // 1024 f32
    float* partials = enorm + K_CODES;                    // 512 f32 (1024 slot)
    short* Eb       = (short*)(partials + 1024);          // 512 KB bf16, 16B-aligned

    vq_prep    <<<256,  256, 0, stream>>>(E, enorm, Eb);
    vq_main    <<<NBLK, 256, 0, stream>>>(X, E, enorm, Eb, out, partials);
    vq_finalize<<<1,    256, 0, stream>>>(partials, out + (size_t)N_ROWS * D_DIM);
}